// Round 4
// baseline (221.152 us; speedup 1.0000x reference)
//
#include <hip/hip_runtime.h>
#include <hip/hip_bf16.h>
#include <stdint.h>

typedef float  f32x4  __attribute__((ext_vector_type(4)));
typedef __bf16 bf16x8 __attribute__((ext_vector_type(8)));
typedef __bf16 bf16x4 __attribute__((ext_vector_type(4)));

#define GRID   1024
#define MROWS  32
#define ITERS  8           // GRID * ITERS * MROWS = 262144 rows
#define ROWB   528         // bf16 LDS row stride in bytes (512 + 16 pad)
#define TILEB  (MROWS * ROWB)

// raw barrier: make this wave's ds_writes visible, do NOT drain vmem
// (avoids __syncthreads()'s implicit s_waitcnt vmcnt(0) -- the round-3 serializer)
#define BAR() do {                                         \
    asm volatile("s_waitcnt lgkmcnt(0)" ::: "memory");     \
    __builtin_amdgcn_s_barrier();                          \
} while (0)

// exp_proj onto {sign(w) * 0.25 * 2^k, k=0..4}; boundaries at 0.25*2^(k+0.5)
__device__ __forceinline__ float qlog(float v) {
    float a = fabsf(v);
    int k = (a >= 0.35355339059327373f)
          + (a >= 0.70710678118654746f)
          + (a >= 1.41421356237309515f)
          + (a >= 2.82842712474619029f);
    float q = 0.25f * (float)(1 << k);
    return (v == 0.0f) ? 0.0f : copysignf(q, v);
}

__global__ __launch_bounds__(512, 4) void lqw_gemm(
    const float* __restrict__ in,    // [262144][256]
    const float* __restrict__ w,     // [256][256]
    const float* __restrict__ bias,  // [256]
    float* __restrict__ out)         // [262144][256]
{
    __shared__ __align__(16) char smem[2 * TILEB];   // 33792 B
    const int tid  = threadIdx.x;
    const int lane = tid & 63;
    const int wv   = tid >> 6;       // wave 0..7 owns 32 output cols
    const int nbase = wv * 32;
    const int lrow = lane & 15;
    const int kgrp = lane >> 4;
    const int k0   = kgrp * 8;

    // ---- register-resident quantized B fragments (one-time, L2-served) ----
    // lane holds n = nbase + nt*16 + lrow, k = kt*32 + k0 + e  (A-operand layout)
    bf16x8 bq[2][8];
    #pragma unroll
    for (int nt = 0; nt < 2; ++nt) {
        const float* wrow = w + (size_t)(nbase + nt * 16 + lrow) * 256;
        #pragma unroll
        for (int kt = 0; kt < 8; ++kt) {
            bf16x8 fr;
            #pragma unroll
            for (int e = 0; e < 8; ++e) fr[e] = (__bf16)qlog(wrow[kt * 32 + k0 + e]);
            bq[nt][kt] = fr;
        }
    }
    // bias vector for swapped-D layout: lane holds n = nbase + nt*16 + kgrp*4 + rg
    f32x4 bv[2];
    #pragma unroll
    for (int nt = 0; nt < 2; ++nt)
        bv[nt] = *(const f32x4*)(bias + nbase + nt * 16 + kgrp * 4);

    const int mt0 = blockIdx.x * ITERS;
    f32x4 sreg[4];

    // coalesced tile load: instr r covers one contiguous 8 KB slab
    #define LOAD_TILE(mt) do {                                             \
        const f32x4* _s = (const f32x4*)(in + (size_t)(mt) * (MROWS*256)); \
        sreg[0] = _s[0*512 + tid]; sreg[1] = _s[1*512 + tid];              \
        sreg[2] = _s[2*512 + tid]; sreg[3] = _s[3*512 + tid];              \
    } while (0)

    // cvt to bf16 + conflict-free row-contiguous ds_write_b64
    #define WRITE_TILE(b) do {                                             \
        char* _d = smem + (b) * TILEB;                                     \
        _Pragma("unroll")                                                  \
        for (int r = 0; r < 4; ++r) {                                      \
            int j = r * 512 + tid;          /* f4 index in 32x256 tile */  \
            bf16x4 v;                                                      \
            v[0] = (__bf16)sreg[r][0]; v[1] = (__bf16)sreg[r][1];          \
            v[2] = (__bf16)sreg[r][2]; v[3] = (__bf16)sreg[r][3];          \
            *(bf16x4*)(_d + (j >> 6) * ROWB + (j & 63) * 8) = v;           \
        }                                                                  \
    } while (0)

    LOAD_TILE(mt0);
    WRITE_TILE(0);
    LOAD_TILE(mt0 + 1);
    BAR();

    for (int t = 0; t < ITERS; ++t) {
        const int b = t & 1;
        if (t + 1 < ITERS) WRITE_TILE(b ^ 1);          // stage tile t+1
        if (t + 2 < ITERS) LOAD_TILE(mt0 + t + 2);     // prefetch tile t+2

        const char* base = smem + b * TILEB;
        f32x4 acc[2][2];
        #pragma unroll
        for (int mi = 0; mi < 2; ++mi)
            #pragma unroll
            for (int nt = 0; nt < 2; ++nt)
                acc[mi][nt] = bv[nt];

        #pragma unroll
        for (int kt = 0; kt < 8; ++kt) {
            bf16x8 a0 = *(const bf16x8*)(base + (size_t)lrow * ROWB + kt * 64 + kgrp * 16);
            bf16x8 a1 = *(const bf16x8*)(base + (size_t)(16 + lrow) * ROWB + kt * 64 + kgrp * 16);
            // swapped operands: D[i=n][j=m] -> lane holds 4 consecutive n
            acc[0][0] = __builtin_amdgcn_mfma_f32_16x16x32_bf16(bq[0][kt], a0, acc[0][0], 0, 0, 0);
            acc[0][1] = __builtin_amdgcn_mfma_f32_16x16x32_bf16(bq[1][kt], a0, acc[0][1], 0, 0, 0);
            acc[1][0] = __builtin_amdgcn_mfma_f32_16x16x32_bf16(bq[0][kt], a1, acc[1][0], 0, 0, 0);
            acc[1][1] = __builtin_amdgcn_mfma_f32_16x16x32_bf16(bq[1][kt], a1, acc[1][1], 0, 0, 0);
        }

        // store: row m = mt*32 + mi*16 + lrow, cols nbase + nt*16 + kgrp*4 .. +3
        const int mt = mt0 + t;
        #pragma unroll
        for (int mi = 0; mi < 2; ++mi) {
            float* orow = out + (size_t)(mt * 32 + mi * 16 + lrow) * 256 + nbase + kgrp * 4;
            #pragma unroll
            for (int nt = 0; nt < 2; ++nt)
                *(f32x4*)(orow + nt * 16) = acc[mi][nt];
        }
        BAR();
    }
}

extern "C" void kernel_launch(void* const* d_in, const int* in_sizes, int n_in,
                              void* d_out, int out_size, void* d_ws, size_t ws_size,
                              hipStream_t stream) {
    const float* in_p   = (const float*)d_in[0];
    const float* w_p    = (const float*)d_in[1];
    const float* bias_p = (const float*)d_in[2];
    float* out_p        = (float*)d_out;
    lqw_gemm<<<GRID, 512, 0, stream>>>(in_p, w_p, bias_p, out_p);
}

// Round 5
// 140.647 us; speedup vs baseline: 1.5724x; 1.5724x over previous
//
#include <hip/hip_runtime.h>
#include <hip/hip_bf16.h>
#include <stdint.h>

typedef float  f32x4  __attribute__((ext_vector_type(4)));
typedef __bf16 bf16x8 __attribute__((ext_vector_type(8)));
typedef __bf16 bf16x4 __attribute__((ext_vector_type(4)));

#define GRID   512
#define MROWS  32
#define ITERS  16          // GRID * ITERS * MROWS = 262144 rows
#define ROWB   528         // bf16 LDS row stride in bytes (512 + 16 pad)
#define TILEB  (MROWS * ROWB)
#define WSB    131072      // quantized-B frag table: 8192 frags * 16 B

// raw barrier: ds ops visible, vmem NOT drained (loads/stores live across it)
#define BAR() do {                                         \
    asm volatile("s_waitcnt lgkmcnt(0)" ::: "memory");     \
    __builtin_amdgcn_s_barrier();                          \
} while (0)

// exp_proj onto {sign(w) * 0.25 * 2^k, k=0..4}; boundaries at 0.25*2^(k+0.5)
__device__ __forceinline__ float qlog(float v) {
    float a = fabsf(v);
    int k = (a >= 0.35355339059327373f)
          + (a >= 0.70710678118654746f)
          + (a >= 1.41421356237309515f)
          + (a >= 2.82842712474619029f);
    float q = 0.25f * (float)(1 << k);
    return (v == 0.0f) ? 0.0f : copysignf(q, v);
}

// kernel 1: quantize weight -> bf16 frag table in ws.
// frag id = ((wv*2+nt)*8 + kt)*64 + lane ; holds w_q[n][k0..k0+7],
// n = (wv*2+nt)*16 + (lane&15), k0 = kt*32 + (lane>>4)*8.
__global__ __launch_bounds__(256) void lqw_quant(
    const float* __restrict__ w, __hip_bfloat16* __restrict__ wsq)
{
    const int gid  = blockIdx.x * 256 + threadIdx.x;   // 0..8191
    const int lane = gid & 63;
    const int kt   = (gid >> 6) & 7;
    const int ntv  = gid >> 9;                         // 0..15
    const float* src = w + (size_t)(ntv * 16 + (lane & 15)) * 256
                         + kt * 32 + (lane >> 4) * 8;
    bf16x8 fr;
    #pragma unroll
    for (int e = 0; e < 8; ++e) fr[e] = (__bf16)qlog(src[e]);
    *(bf16x8*)((char*)wsq + (size_t)gid * 16) = fr;
}

template<bool USE_WS>
__global__ __launch_bounds__(512, 4) void lqw_gemm(
    const float* __restrict__ in,    // [262144][256]
    const float* __restrict__ w,     // [256][256]
    const float* __restrict__ bias,  // [256]
    const __hip_bfloat16* __restrict__ wsq,
    float* __restrict__ out)         // [262144][256]
{
    __shared__ __align__(16) char smem[2 * TILEB];   // 33792 B
    const int tid  = threadIdx.x;
    const int lane = tid & 63;
    const int wv   = tid >> 6;       // wave 0..7 owns 32 output cols
    const int nbase = wv * 32;
    const int lrow = lane & 15;
    const int kgrp = lane >> 4;

    // ---- quantized B fragments: coalesced load from ws (or self-quant) ----
    bf16x8 bq[2][8];
    if (USE_WS) {
        const bf16x8* wq = (const bf16x8*)wsq;
        #pragma unroll
        for (int nt = 0; nt < 2; ++nt)
            #pragma unroll
            for (int kt = 0; kt < 8; ++kt)
                bq[nt][kt] = wq[(size_t)((wv * 2 + nt) * 8 + kt) * 64 + lane];
    } else {
        #pragma unroll
        for (int nt = 0; nt < 2; ++nt) {
            const float* wrow = w + (size_t)(nbase + nt * 16 + lrow) * 256;
            #pragma unroll
            for (int kt = 0; kt < 8; ++kt) {
                bf16x8 fr;
                #pragma unroll
                for (int e = 0; e < 8; ++e)
                    fr[e] = (__bf16)qlog(wrow[kt * 32 + kgrp * 8 + e]);
                bq[nt][kt] = fr;
            }
        }
    }
    // bias for swapped-D layout: lane holds n = nbase + nt*16 + kgrp*4 + rg
    f32x4 bv[2];
    #pragma unroll
    for (int nt = 0; nt < 2; ++nt)
        bv[nt] = *(const f32x4*)(bias + nbase + nt * 16 + kgrp * 4);

    const int mt0 = blockIdx.x * ITERS;

    #define LOAD_TILE(S, mt) do {                                          \
        const f32x4* _s = (const f32x4*)(in + (size_t)(mt) * (MROWS*256)); \
        S[0] = _s[0*512 + tid]; S[1] = _s[1*512 + tid];                    \
        S[2] = _s[2*512 + tid]; S[3] = _s[3*512 + tid];                    \
    } while (0)

    #define WRITE_TILE(b, S) do {                                          \
        char* _d = smem + (b) * TILEB;                                     \
        _Pragma("unroll")                                                  \
        for (int r = 0; r < 4; ++r) {                                      \
            int j = r * 512 + tid;                                         \
            bf16x4 v;                                                      \
            v[0] = (__bf16)S[r][0]; v[1] = (__bf16)S[r][1];                \
            v[2] = (__bf16)S[r][2]; v[3] = (__bf16)S[r][3];                \
            *(bf16x4*)(_d + (j >> 6) * ROWB + (j & 63) * 8) = v;           \
        }                                                                  \
    } while (0)

    #define COMPUTE(b, mt) do {                                                             \
        const char* base = smem + (b) * TILEB;                                              \
        f32x4 acc[2][2];                                                                    \
        _Pragma("unroll")                                                                   \
        for (int mi = 0; mi < 2; ++mi)                                                      \
            _Pragma("unroll")                                                               \
            for (int nt = 0; nt < 2; ++nt) acc[mi][nt] = bv[nt];                            \
        _Pragma("unroll")                                                                   \
        for (int kt = 0; kt < 8; ++kt) {                                                    \
            bf16x8 a0 = *(const bf16x8*)(base + (size_t)lrow * ROWB + kt * 64 + kgrp * 16); \
            bf16x8 a1 = *(const bf16x8*)(base + (size_t)(16 + lrow) * ROWB + kt * 64 + kgrp * 16); \
            acc[0][0] = __builtin_amdgcn_mfma_f32_16x16x32_bf16(bq[0][kt], a0, acc[0][0], 0, 0, 0); \
            acc[0][1] = __builtin_amdgcn_mfma_f32_16x16x32_bf16(bq[1][kt], a0, acc[0][1], 0, 0, 0); \
            acc[1][0] = __builtin_amdgcn_mfma_f32_16x16x32_bf16(bq[0][kt], a1, acc[1][0], 0, 0, 0); \
            acc[1][1] = __builtin_amdgcn_mfma_f32_16x16x32_bf16(bq[1][kt], a1, acc[1][1], 0, 0, 0); \
        }                                                                                   \
        _Pragma("unroll")                                                                   \
        for (int mi = 0; mi < 2; ++mi) {                                                    \
            float* orow = out + (size_t)((mt) * 32 + mi * 16 + lrow) * 256 + nbase + kgrp * 4; \
            *(f32x4*)(orow)      = acc[mi][0];                                              \
            *(f32x4*)(orow + 16) = acc[mi][1];                                              \
        }                                                                                   \
    } while (0)

    // ---- 2-deep pipelined prologue ----
    f32x4 sA[4], sB[4];
    LOAD_TILE(sA, mt0);
    LOAD_TILE(sB, mt0 + 1);
    WRITE_TILE(0, sA);
    LOAD_TILE(sA, mt0 + 2);
    BAR();

    #pragma unroll 1
    for (int t = 0; t < ITERS; t += 2) {
        // even phase: compute tile t from buf0; stage t+1; prefetch t+3
        WRITE_TILE(1, sB);
        if (t + 3 < ITERS) LOAD_TILE(sB, mt0 + t + 3);
        COMPUTE(0, mt0 + t);
        BAR();
        // odd phase: compute tile t+1 from buf1; stage t+2; prefetch t+4
        if (t + 2 < ITERS) WRITE_TILE(0, sA);
        if (t + 4 < ITERS) LOAD_TILE(sA, mt0 + t + 4);
        COMPUTE(1, mt0 + t + 1);
        BAR();
    }
}

extern "C" void kernel_launch(void* const* d_in, const int* in_sizes, int n_in,
                              void* d_out, int out_size, void* d_ws, size_t ws_size,
                              hipStream_t stream) {
    const float* in_p   = (const float*)d_in[0];
    const float* w_p    = (const float*)d_in[1];
    const float* bias_p = (const float*)d_in[2];
    float* out_p        = (float*)d_out;
    if (ws_size >= WSB) {
        __hip_bfloat16* wsq = (__hip_bfloat16*)d_ws;
        lqw_quant<<<32, 256, 0, stream>>>(w_p, wsq);
        lqw_gemm<true><<<GRID, 512, 0, stream>>>(in_p, w_p, bias_p, wsq, out_p);
    } else {
        lqw_gemm<false><<<GRID, 512, 0, stream>>>(in_p, w_p, bias_p, nullptr, out_p);
    }
}